// Round 1
// baseline (470.919 us; speedup 1.0000x reference)
//
#include <hip/hip_runtime.h>

// ---------------------------------------------------------------------------
// MHA forward: x[4,2048,768] @ w_qkv[768,2304] -> split heads -> softmax(QK^T/8)V
//              -> @ w_proj[768,768] + b_proj. fp32 in/out, bf16 MFMA internally.
// ---------------------------------------------------------------------------

typedef short s16x8 __attribute__((ext_vector_type(8)));   // 8 bf16 bit-patterns (4 VGPR)
typedef short s16x4 __attribute__((ext_vector_type(4)));   // 4 bf16 (8B)
typedef float f32x4 __attribute__((ext_vector_type(4)));

#define NHEADS 12
#define HDIM   64
#define SEQ    2048
#define BATCH  4
#define DMODEL 768
#define MTOT   (BATCH*SEQ)     /* 8192 */
#define K3     (3*DMODEL)      /* 2304 */
#define ATT_SCALE 0.125f

__device__ __forceinline__ short f2bf(float f) {
  unsigned int u = __builtin_bit_cast(unsigned int, f);
  u += 0x7fffu + ((u >> 16) & 1u);   // round-to-nearest-even
  return (short)(u >> 16);
}

__device__ __forceinline__ f32x4 mfma16(s16x8 a, s16x8 b, f32x4 c) {
  return __builtin_amdgcn_mfma_f32_16x16x32_bf16(a, b, c, 0, 0, 0);
}

// ---- cast fp32 -> bf16, 4 elems/thread, vectorized -------------------------
__global__ __launch_bounds__(256) void k_cast4(const float* __restrict__ in,
                                               short* __restrict__ out, int n4) {
  int i = blockIdx.x * 256 + threadIdx.x;
  if (i < n4) {
    float4 f = reinterpret_cast<const float4*>(in)[i];
    s16x4 v;
    v[0] = f2bf(f.x); v[1] = f2bf(f.y); v[2] = f2bf(f.z); v[3] = f2bf(f.w);
    reinterpret_cast<s16x4*>(out)[i] = v;
  }
}

// ---- transposed cast: in[768][C] fp32 -> out[C][768] bf16 ------------------
__global__ __launch_bounds__(256) void k_transpose768(const float* __restrict__ in,
                                                      short* __restrict__ out, int C) {
  int o = blockIdx.x * 256 + threadIdx.x;   // o = c*768 + r  (coalesced writes)
  if (o < C * DMODEL) {
    int c = o / DMODEL;
    int r = o - c * DMODEL;
    out[o] = f2bf(in[r * C + c]);
  }
}

// ---- QKV GEMM: Xb[8192][768] @ WqkvT[2304][768]^T, scatter epilogue --------
// 64x64 tile, BK=32, 4 waves each computing a 32x32 quadrant (2x2 16x16 frags)
__global__ __launch_bounds__(256) void k_gemm_qkv(const short* __restrict__ Xb,
                                                  const short* __restrict__ WT,
                                                  short* __restrict__ Qb,
                                                  short* __restrict__ Kb,
                                                  short* __restrict__ Vt) {
  __shared__ short As[64][40];   // pad +8: stride 80B = 20 banks -> 2-way (free)
  __shared__ short Bs[64][40];   // Bs[n][k] (WT already transposed)
  const int tid = threadIdx.x;
  const int m0 = blockIdx.y * 64, n0 = blockIdx.x * 64;
  const int lane = tid & 63, w = tid >> 6;
  const int wr = w >> 1, wc = w & 1;
  const int g = lane >> 4, r16 = lane & 15;
  const int lr = tid >> 2;            // staging row 0..63
  const int lk = (tid & 3) * 8;       // staging k-offset {0,8,16,24}

  f32x4 acc[2][2] = {};

  for (int k0 = 0; k0 < DMODEL; k0 += 32) {
    s16x8 av = *reinterpret_cast<const s16x8*>(&Xb[(m0 + lr) * DMODEL + k0 + lk]);
    s16x8 bv = *reinterpret_cast<const s16x8*>(&WT[(n0 + lr) * DMODEL + k0 + lk]);
    __syncthreads();
    *reinterpret_cast<s16x8*>(&As[lr][lk]) = av;
    *reinterpret_cast<s16x8*>(&Bs[lr][lk]) = bv;
    __syncthreads();
    s16x8 a0 = *reinterpret_cast<const s16x8*>(&As[wr * 32 + r16][g * 8]);
    s16x8 a1 = *reinterpret_cast<const s16x8*>(&As[wr * 32 + 16 + r16][g * 8]);
    s16x8 b0 = *reinterpret_cast<const s16x8*>(&Bs[wc * 32 + r16][g * 8]);
    s16x8 b1 = *reinterpret_cast<const s16x8*>(&Bs[wc * 32 + 16 + r16][g * 8]);
    acc[0][0] = mfma16(a0, b0, acc[0][0]);
    acc[0][1] = mfma16(a0, b1, acc[0][1]);
    acc[1][0] = mfma16(a1, b0, acc[1][0]);
    acc[1][1] = mfma16(a1, b1, acc[1][1]);
  }

  // epilogue: route columns into Q[b,h,n,d] / K[b,h,n,d] / V^T[b,h,d,n]
  for (int i = 0; i < 2; ++i) {
    for (int jn = 0; jn < 2; ++jn) {
      const int c = n0 + wc * 32 + jn * 16 + r16;   // global col (wave-uniform segment)
      for (int rr = 0; rr < 4; ++rr) {
        const int m = m0 + wr * 32 + i * 16 + g * 4 + rr;
        const short val = f2bf(acc[i][jn][rr]);
        const int bb = m >> 11, ns = m & 2047;
        if (c < DMODEL) {
          const int h = c >> 6, d = c & 63;
          Qb[((bb * NHEADS + h) * SEQ + ns) * HDIM + d] = val;
        } else if (c < 2 * DMODEL) {
          const int cc = c - DMODEL, h = cc >> 6, d = cc & 63;
          Kb[((bb * NHEADS + h) * SEQ + ns) * HDIM + d] = val;
        } else {
          const int cc = c - 2 * DMODEL, h = cc >> 6, d = cc & 63;
          Vt[((bb * NHEADS + h) * HDIM + d) * SEQ + ns] = val;
        }
      }
    }
  }
}

// ---- flash attention: per wave one 16-row q tile, KBLK=32 ------------------
__global__ __launch_bounds__(256) void k_attn(const short* __restrict__ Qb,
                                              const short* __restrict__ Kb,
                                              const short* __restrict__ Vt,
                                              short* __restrict__ Ctx) {
  __shared__ short Plds[4][16][40];   // wave-private P buffer, pad -> 2-way banks
  const int tid = threadIdx.x, lane = tid & 63, w = tid >> 6;
  const int g = lane >> 4, r16 = lane & 15;
  const int bh = blockIdx.y;                 // 0..47
  const int bb = bh / NHEADS, h = bh - bb * NHEADS;
  const int q0 = blockIdx.x * 64 + w * 16;

  const short* Qp = Qb + (size_t)bh * SEQ * HDIM;
  const short* Kp = Kb + (size_t)bh * SEQ * HDIM;
  const short* Vp = Vt + (size_t)bh * HDIM * SEQ;

  // Q fragments (row = r16, d contiguous in 8-chunks)
  s16x8 aq0 = *reinterpret_cast<const s16x8*>(&Qp[(q0 + r16) * HDIM + g * 8]);
  s16x8 aq1 = *reinterpret_cast<const s16x8*>(&Qp[(q0 + r16) * HDIM + 32 + g * 8]);

  float mrun[4], lrun[4];
  f32x4 accv[4] = {};
#pragma unroll
  for (int rr = 0; rr < 4; ++rr) { mrun[rr] = -1e30f; lrun[rr] = 0.f; }

  for (int kb = 0; kb < SEQ; kb += 32) {
    f32x4 s0 = {}, s1 = {};
    {
      s16x8 bk;
      bk = *reinterpret_cast<const s16x8*>(&Kp[(kb + r16) * HDIM + g * 8]);
      s0 = mfma16(aq0, bk, s0);
      bk = *reinterpret_cast<const s16x8*>(&Kp[(kb + r16) * HDIM + 32 + g * 8]);
      s0 = mfma16(aq1, bk, s0);
      bk = *reinterpret_cast<const s16x8*>(&Kp[(kb + 16 + r16) * HDIM + g * 8]);
      s1 = mfma16(aq0, bk, s1);
      bk = *reinterpret_cast<const s16x8*>(&Kp[(kb + 16 + r16) * HDIM + 32 + g * 8]);
      s1 = mfma16(aq1, bk, s1);
    }
#pragma unroll
    for (int rr = 0; rr < 4; ++rr) {
      float v0 = s0[rr] * ATT_SCALE, v1 = s1[rr] * ATT_SCALE;
      float mx = fmaxf(v0, v1);
      mx = fmaxf(mx, __shfl_xor(mx, 1));
      mx = fmaxf(mx, __shfl_xor(mx, 2));
      mx = fmaxf(mx, __shfl_xor(mx, 4));
      mx = fmaxf(mx, __shfl_xor(mx, 8));
      float mnew = fmaxf(mrun[rr], mx);
      float alpha = __expf(mrun[rr] - mnew);
      float p0 = __expf(v0 - mnew);
      float p1 = __expf(v1 - mnew);
      mrun[rr] = mnew;
      float rs = p0 + p1;
      rs += __shfl_xor(rs, 1);
      rs += __shfl_xor(rs, 2);
      rs += __shfl_xor(rs, 4);
      rs += __shfl_xor(rs, 8);
      lrun[rr] = lrun[rr] * alpha + rs;
      accv[0][rr] *= alpha; accv[1][rr] *= alpha;
      accv[2][rr] *= alpha; accv[3][rr] *= alpha;
      Plds[w][g * 4 + rr][r16]      = f2bf(p0);
      Plds[w][g * 4 + rr][16 + r16] = f2bf(p1);
    }
    // PV: A = P (row=q via r16, k-slot = key), B = V^T (col=d via r16)
    s16x8 pa = *reinterpret_cast<const s16x8*>(&Plds[w][r16][g * 8]);
#pragma unroll
    for (int dc = 0; dc < 4; ++dc) {
      s16x8 bv = *reinterpret_cast<const s16x8*>(&Vp[(dc * 16 + r16) * SEQ + kb + g * 8]);
      accv[dc] = mfma16(pa, bv, accv[dc]);
    }
  }

  // write context [b][n][h*64+d] bf16
#pragma unroll
  for (int dc = 0; dc < 4; ++dc) {
#pragma unroll
    for (int rr = 0; rr < 4; ++rr) {
      float o = accv[dc][rr] / lrun[rr];
      Ctx[(size_t)(bb * SEQ + q0 + g * 4 + rr) * DMODEL + h * HDIM + dc * 16 + r16] = f2bf(o);
    }
  }
}

// ---- proj GEMM: Ctx[8192][768] @ WprojT[768][768]^T + bias -> fp32 out -----
__global__ __launch_bounds__(256) void k_gemm_proj(const short* __restrict__ Ctx,
                                                   const short* __restrict__ WT,
                                                   const float* __restrict__ bias,
                                                   float* __restrict__ Out) {
  __shared__ short As[64][40];
  __shared__ short Bs[64][40];
  const int tid = threadIdx.x;
  const int m0 = blockIdx.y * 64, n0 = blockIdx.x * 64;
  const int lane = tid & 63, w = tid >> 6;
  const int wr = w >> 1, wc = w & 1;
  const int g = lane >> 4, r16 = lane & 15;
  const int lr = tid >> 2;
  const int lk = (tid & 3) * 8;

  f32x4 acc[2][2] = {};

  for (int k0 = 0; k0 < DMODEL; k0 += 32) {
    s16x8 av = *reinterpret_cast<const s16x8*>(&Ctx[(m0 + lr) * DMODEL + k0 + lk]);
    s16x8 bv = *reinterpret_cast<const s16x8*>(&WT[(n0 + lr) * DMODEL + k0 + lk]);
    __syncthreads();
    *reinterpret_cast<s16x8*>(&As[lr][lk]) = av;
    *reinterpret_cast<s16x8*>(&Bs[lr][lk]) = bv;
    __syncthreads();
    s16x8 a0 = *reinterpret_cast<const s16x8*>(&As[wr * 32 + r16][g * 8]);
    s16x8 a1 = *reinterpret_cast<const s16x8*>(&As[wr * 32 + 16 + r16][g * 8]);
    s16x8 b0 = *reinterpret_cast<const s16x8*>(&Bs[wc * 32 + r16][g * 8]);
    s16x8 b1 = *reinterpret_cast<const s16x8*>(&Bs[wc * 32 + 16 + r16][g * 8]);
    acc[0][0] = mfma16(a0, b0, acc[0][0]);
    acc[0][1] = mfma16(a0, b1, acc[0][1]);
    acc[1][0] = mfma16(a1, b0, acc[1][0]);
    acc[1][1] = mfma16(a1, b1, acc[1][1]);
  }

  for (int i = 0; i < 2; ++i) {
    for (int jn = 0; jn < 2; ++jn) {
      const int c = n0 + wc * 32 + jn * 16 + r16;
      const float bv = bias[c];
      for (int rr = 0; rr < 4; ++rr) {
        const int m = m0 + wr * 32 + i * 16 + g * 4 + rr;
        Out[(size_t)m * DMODEL + c] = acc[i][jn][rr] + bv;
      }
    }
  }
}

extern "C" void kernel_launch(void* const* d_in, const int* in_sizes, int n_in,
                              void* d_out, int out_size, void* d_ws, size_t ws_size,
                              hipStream_t stream) {
  const float* x      = (const float*)d_in[0];
  const float* w_qkv  = (const float*)d_in[1];
  const float* w_proj = (const float*)d_in[2];
  const float* b_proj = (const float*)d_in[3];
  float* out = (float*)d_out;

  char* ws = (char*)d_ws;
  const size_t SZ_X = (size_t)MTOT * DMODEL * 2;   // 12.58 MB
  short* Xb     = (short*)ws;                 ws += SZ_X;
  short* WqkvT  = (short*)ws;                 ws += (size_t)K3 * DMODEL * 2;
  short* WprojT = (short*)ws;                 ws += (size_t)DMODEL * DMODEL * 2;
  short* Qb     = (short*)ws;                 ws += SZ_X;
  short* Kb     = (short*)ws;                 ws += SZ_X;
  short* Vt     = (short*)ws;                 ws += SZ_X;
  short* Ctxb   = Xb;   // alias: Xb dead after QKV GEMM  (total ws use ~55 MB)

  k_cast4<<<(MTOT * DMODEL / 4) / 256, 256, 0, stream>>>(x, Xb, MTOT * DMODEL / 4);
  k_transpose768<<<(K3 * DMODEL + 255) / 256, 256, 0, stream>>>(w_qkv, WqkvT, K3);
  k_transpose768<<<(DMODEL * DMODEL + 255) / 256, 256, 0, stream>>>(w_proj, WprojT, DMODEL);

  k_gemm_qkv<<<dim3(K3 / 64, MTOT / 64), 256, 0, stream>>>(Xb, WqkvT, Qb, Kb, Vt);
  k_attn<<<dim3(SEQ / 64, BATCH * NHEADS), 256, 0, stream>>>(Qb, Kb, Vt, Ctxb);
  k_gemm_proj<<<dim3(DMODEL / 64, MTOT / 64), 256, 0, stream>>>(Ctxb, WprojT, b_proj, out);
}